// Round 3
// baseline (222.244 us; speedup 1.0000x reference)
//
#include <hip/hip_runtime.h>

typedef _Float16 f16;
typedef __attribute__((ext_vector_type(8))) _Float16 f16x8;
typedef __attribute__((ext_vector_type(4))) float f32x4;

#define XS 136            // padded LDS row stride in f16 elems (128 + 8)
#define NEGV (-1e30f)

// ---------- helpers ----------

// async global->LDS, 16B per lane; LDS dest = wave-uniform base + lane*16
__device__ __forceinline__ void gl_lds16(const f16* g, f16* l) {
  __builtin_amdgcn_global_load_lds(
      (const __attribute__((address_space(1))) unsigned int*)(g),
      (__attribute__((address_space(3))) unsigned int*)(l), 16, 0, 0);
}

// stage one 16KB half of a fragment-ordered W matrix into Ws (8192 f16)
// 8-wave version: each wave stages 2 chunks of 1KB.
__device__ __forceinline__ void stage_w_half(const f16* __restrict__ Wf_half,
                                             f16* Ws, int wave, int lane) {
#pragma unroll
  for (int c = 0; c < 2; ++c) {
    int chunk = wave * 2 + c;                  // 16 chunks of 1KB
    gl_lds16(Wf_half + chunk * 512 + lane * 8, Ws + chunk * 512);
  }
}

__device__ __forceinline__ void stage_emb(const int* __restrict__ ids,
                                          const float* __restrict__ emb,
                                          f16* Xs, int tid) {
  // tokens x 128 f32 -> f16 LDS. thread: token tid/4 (wave-private rows).
  int t = tid >> 2, seg = tid & 3;
  int id = ids[t];
  const float4* src = (const float4*)(emb + (size_t)id * 128 + seg * 32);
  f16x8* dst = (f16x8*)(Xs + t * XS + seg * 32);
#pragma unroll
  for (int i = 0; i < 4; ++i) {
    float4 v0 = src[2 * i], v1 = src[2 * i + 1];
    f16x8 o;
    o[0] = (f16)v0.x; o[1] = (f16)v0.y; o[2] = (f16)v0.z; o[3] = (f16)v0.w;
    o[4] = (f16)v1.x; o[5] = (f16)v1.y; o[6] = (f16)v1.z; o[7] = (f16)v1.w;
    dst[i] = o;
  }
}

__device__ __forceinline__ void load_afrag(f16x8* afrag, const f16* Xs,
                                           int wave, int lane) {
  const int r = lane & 15, quad = lane >> 4;
#pragma unroll
  for (int k = 0; k < 4; ++k)
    afrag[k] = *(const f16x8*)(Xs + (wave * 16 + r) * XS + quad * 8 + k * 32);
}

// 4 n-tiles from the currently staged W half (conflict-free contiguous reads)
__device__ __forceinline__ void half_mfma(f32x4* acc4, const f16x8* afrag,
                                          const f16* Ws, int lane) {
#pragma unroll
  for (int nt = 0; nt < 4; ++nt) {
    f32x4 c = {0.f, 0.f, 0.f, 0.f};
#pragma unroll
    for (int k = 0; k < 4; ++k) {
      f16x8 b = *(const f16x8*)(Ws + ((nt * 4 + k) * 64 + lane) * 8);
      c = __builtin_amdgcn_mfma_f32_16x16x32_f16(afrag[k], b, c, 0, 0, 0);
    }
    acc4[nt] = c;
  }
}

// bias + relu + layernorm, write h back to Xs (wave-private rows)
__device__ __forceinline__ void epilogue_ln(f32x4* acc, int wave, int lane, f16* Xs,
                                            const float* __restrict__ bias,
                                            const float* __restrict__ lnw,
                                            const float* __restrict__ lnb) {
  const int r = lane & 15, quad = lane >> 4;
  float s1[4] = {0, 0, 0, 0}, s2[4] = {0, 0, 0, 0};
#pragma unroll
  for (int nt = 0; nt < 8; ++nt) {
    float bv = bias[nt * 16 + r];
#pragma unroll
    for (int g = 0; g < 4; ++g) {
      float z = fmaxf(acc[nt][g] + bv, 0.f);
      acc[nt][g] = z; s1[g] += z; s2[g] += z * z;
    }
  }
#pragma unroll
  for (int off = 1; off < 16; off <<= 1) {
#pragma unroll
    for (int g = 0; g < 4; ++g) {
      s1[g] += __shfl_xor(s1[g], off);
      s2[g] += __shfl_xor(s2[g], off);
    }
  }
  float mean[4], rstd[4];
#pragma unroll
  for (int g = 0; g < 4; ++g) {
    mean[g] = s1[g] * (1.f / 128.f);
    rstd[g] = rsqrtf(s2[g] * (1.f / 128.f) - mean[g] * mean[g] + 1e-5f);
  }
#pragma unroll
  for (int nt = 0; nt < 8; ++nt) {
    float w = lnw[nt * 16 + r], bb = lnb[nt * 16 + r];
#pragma unroll
    for (int g = 0; g < 4; ++g) {
      float h = (acc[nt][g] - mean[g]) * rstd[g] * w + bb;
      Xs[(wave * 16 + quad * 4 + g) * XS + nt * 16 + r] = (f16)h;
    }
  }
}

// ---------- kernels ----------

// W[k][n] f32 -> fragment-ordered f16: out[((nt*4+k)*64 + quad*16 + r)*8 + j]
//   = W[k*32 + quad*8 + j][nt*16 + r]
__global__ __launch_bounds__(256) void prep_kernel(
    const float* __restrict__ qW1, const float* __restrict__ qW2,
    const float* __restrict__ dW1, const float* __restrict__ dW2,
    f16* __restrict__ out) {
  int mat = blockIdx.x >> 3;   // 8 blocks per matrix
  int blk = blockIdx.x & 7;
  const float* W = mat == 0 ? qW1 : mat == 1 ? qW2 : mat == 2 ? dW1 : dW2;
  int u = blk * 256 + threadIdx.x;                 // fragment-lane unit 0..2047
  int r = u & 15, quad = (u >> 4) & 3, k = (u >> 6) & 3, nt = u >> 8;
  const float* src = W + (k * 32 + quad * 8) * 128 + nt * 16 + r;
  f16x8 o;
#pragma unroll
  for (int j = 0; j < 8; ++j) o[j] = (f16)src[j * 128];
  *(f16x8*)(out + (size_t)mat * 16384 + (size_t)u * 8) = o;
}

__global__ __launch_bounds__(256) void qencode_kernel(
    const int* __restrict__ qids, const int* __restrict__ qmask,
    const float* __restrict__ emb,
    const f16* __restrict__ W1f, const float* __restrict__ b1,
    const f16* __restrict__ W2f, const float* __restrict__ b2,
    const float* __restrict__ lnw, const float* __restrict__ lnb,
    f16* __restrict__ qv) {
  __shared__ __align__(16) f16 Xs[64 * XS];
  __shared__ __align__(16) f16 Ws[8192];
  const int tid = threadIdx.x, wave = tid >> 6, lane = tid & 63;
  const int b = blockIdx.x;
  stage_emb(qids + b * 64, emb, Xs, tid);
  // 4-wave staging: each wave stages 4 chunks
#pragma unroll
  for (int c = 0; c < 4; ++c) {
    int chunk = wave * 4 + c;
    gl_lds16(W1f + chunk * 512 + lane * 8, Ws + chunk * 512);
  }
  __syncthreads();                       // W1h0 ready
  f32x4 acc[8];
  f16x8 afrag[4];
  load_afrag(afrag, Xs, wave, lane);
  half_mfma(acc, afrag, Ws, lane);
  __syncthreads();                       // h0 reads done
#pragma unroll
  for (int c = 0; c < 4; ++c) {
    int chunk = wave * 4 + c;
    gl_lds16(W1f + 8192 + chunk * 512 + lane * 8, Ws + chunk * 512);
  }
  __syncthreads();                       // W1h1 ready
  half_mfma(acc + 4, afrag, Ws, lane);
  __syncthreads();                       // h1 reads done
#pragma unroll
  for (int c = 0; c < 4; ++c) {
    int chunk = wave * 4 + c;
    gl_lds16(W2f + chunk * 512 + lane * 8, Ws + chunk * 512);
  }
  epilogue_ln(acc, wave, lane, Xs, b1, lnw, lnb);
  __syncthreads();                       // W2h0 ready
  load_afrag(afrag, Xs, wave, lane);
  half_mfma(acc, afrag, Ws, lane);
  __syncthreads();
#pragma unroll
  for (int c = 0; c < 4; ++c) {
    int chunk = wave * 4 + c;
    gl_lds16(W2f + 8192 + chunk * 512 + lane * 8, Ws + chunk * 512);
  }
  __syncthreads();
  half_mfma(acc + 4, afrag, Ws, lane);
  epilogue_ln(acc, wave, lane, Xs, b2, lnw, lnb);
  __syncthreads();                       // all rows visible
  // masked copy-out in A-fragment order: qv[b][u][8]
#pragma unroll
  for (int i = 0; i < 4; ++i) {
    int u = tid + i * 256;               // 1024 units of f16x8
    int r = u & 15, quad = (u >> 4) & 3, k = (u >> 6) & 3, mt = u >> 8;
    int row = mt * 16 + r;
    f16 m = (f16)(float)qmask[b * 64 + row];
    f16x8 v = *(const f16x8*)(Xs + row * XS + k * 32 + quad * 8);
#pragma unroll
    for (int j = 0; j < 8; ++j) v[j] = v[j] * m;
    *(f16x8*)(qv + (size_t)b * 8192 + (size_t)u * 8) = v;
  }
}

// 512 threads / 8 waves, 2 doc-chunks (128 doc rows) per block.
// One W-staging + barrier chain serves both chunks.
__global__ __launch_bounds__(512, 6) void docsim_kernel(
    const int* __restrict__ dids, const int* __restrict__ dmask,
    const float* __restrict__ emb,
    const f16* __restrict__ W1f, const float* __restrict__ b1,
    const f16* __restrict__ W2f, const float* __restrict__ b2,
    const float* __restrict__ lnw, const float* __restrict__ lnb,
    const f16* __restrict__ qv, float* __restrict__ partials) {
  __shared__ __align__(16) f16 Xs[128 * XS];   // 34,816 B
  __shared__ __align__(16) f16 Ws[8192];       // 16,384 B
  const int tid = threadIdx.x, wave = tid >> 6, lane = tid & 63;
  const int b = blockIdx.x >> 5;        // batch (2048 blocks = 64 b x 32)
  const int dc0 = (blockIdx.x & 31) * 2; // first of this block's 2 doc chunks
  const int g = wave >> 2;              // chunk index within block (0/1)
  const int qt = wave & 3;              // q-row tile for sim
  const int r = lane & 15, quad = lane >> 4;
  // doc-mask values for this lane's sim columns — early, independent loads
  float mv[4];
#pragma unroll
  for (int nt = 0; nt < 4; ++nt)
    mv[nt] = (float)dmask[(size_t)b * 4096 + (dc0 + g) * 64 + nt * 16 + r];
  stage_emb(dids + (size_t)b * 4096 + dc0 * 64, emb, Xs, tid);  // 128 rows
  stage_w_half(W1f, Ws, wave, lane);
  __syncthreads();                       // W1h0 + emb ready
  f32x4 acc[8];
  f16x8 afrag[4];
  load_afrag(afrag, Xs, wave, lane);
  half_mfma(acc, afrag, Ws, lane);
  __syncthreads();                       // h0 reads done
  stage_w_half(W1f + 8192, Ws, wave, lane);
  __syncthreads();                       // W1h1 ready
  half_mfma(acc + 4, afrag, Ws, lane);
  __syncthreads();                       // h1 reads done
  stage_w_half(W2f, Ws, wave, lane);     // async; overlaps epilogue
  epilogue_ln(acc, wave, lane, Xs, b1, lnw, lnb);
  __syncthreads();                       // W2h0 ready
  load_afrag(afrag, Xs, wave, lane);
  half_mfma(acc, afrag, Ws, lane);
  __syncthreads();
  stage_w_half(W2f + 8192, Ws, wave, lane);
  __syncthreads();
  half_mfma(acc + 4, afrag, Ws, lane);
  epilogue_ln(acc, wave, lane, Xs, b2, lnw, lnb);
  // sim A-fragments (qv, fragment-ordered) straight from global — issue before
  // the barrier so the loads fly while waves sync.
  f16x8 qfrag[4];
#pragma unroll
  for (int k = 0; k < 4; ++k) {
    int u = (qt * 4 + k) * 64 + quad * 16 + r;
    qfrag[k] = *(const f16x8*)(qv + (size_t)b * 8192 + (size_t)u * 8);
  }
  __syncthreads();                       // all dv rows visible
  float rowmax[4] = {NEGV, NEGV, NEGV, NEGV};
#pragma unroll
  for (int nt = 0; nt < 4; ++nt) {
    f32x4 c = {0.f, 0.f, 0.f, 0.f};
#pragma unroll
    for (int k = 0; k < 4; ++k) {
      f16x8 bfrag = *(const f16x8*)(Xs + (g * 64 + nt * 16 + r) * XS + quad * 8 + k * 32);
      c = __builtin_amdgcn_mfma_f32_16x16x32_f16(qfrag[k], bfrag, c, 0, 0, 0);
    }
#pragma unroll
    for (int gg = 0; gg < 4; ++gg) {
      float v = (mv[nt] != 0.f) ? c[gg] : NEGV;
      rowmax[gg] = fmaxf(rowmax[gg], v);
    }
  }
#pragma unroll
  for (int off = 1; off < 16; off <<= 1) {
#pragma unroll
    for (int gg = 0; gg < 4; ++gg)
      rowmax[gg] = fmaxf(rowmax[gg], __shfl_xor(rowmax[gg], off));
  }
  if (r == 0) {
#pragma unroll
    for (int gg = 0; gg < 4; ++gg) {
      int q = qt * 16 + quad * 4 + gg;
      partials[((size_t)b * 64 + q) * 64 + dc0 + g] = rowmax[gg];
    }
  }
}

__global__ __launch_bounds__(256) void reduce_kernel(
    const float* __restrict__ partials, float* __restrict__ out) {
  __shared__ float red[64][4];
  const int b = blockIdx.x, tid = threadIdx.x;
  const int q = tid >> 2, seg = tid & 3;
  const float4* p = (const float4*)(partials + ((size_t)b * 64 + q) * 64 + seg * 16);
  float m = NEGV;
#pragma unroll
  for (int i = 0; i < 4; ++i) {
    float4 v = p[i];
    m = fmaxf(m, fmaxf(fmaxf(v.x, v.y), fmaxf(v.z, v.w)));
  }
  red[q][seg] = m;
  __syncthreads();
  if (tid < 64) {
    float qm = fmaxf(fmaxf(red[tid][0], red[tid][1]), fmaxf(red[tid][2], red[tid][3]));
    float s = qm;
#pragma unroll
    for (int off = 1; off < 64; off <<= 1) s += __shfl_xor(s, off);
    if (tid == 0) out[b] = s;
  }
}

// ---------- launch ----------

extern "C" void kernel_launch(void* const* d_in, const int* in_sizes, int n_in,
                              void* d_out, int out_size, void* d_ws, size_t ws_size,
                              hipStream_t stream) {
  const int* query_ids  = (const int*)d_in[0];
  const int* doc_ids    = (const int*)d_in[1];
  const int* query_mask = (const int*)d_in[2];
  const int* doc_mask   = (const int*)d_in[3];
  const float* q_emb = (const float*)d_in[4];
  const float* qW1 = (const float*)d_in[5];
  const float* qb1 = (const float*)d_in[6];
  const float* qW2 = (const float*)d_in[7];
  const float* qb2 = (const float*)d_in[8];
  const float* q_lnw = (const float*)d_in[9];
  const float* q_lnb = (const float*)d_in[10];
  const float* d_emb = (const float*)d_in[11];
  const float* dW1 = (const float*)d_in[12];
  const float* db1 = (const float*)d_in[13];
  const float* dW2 = (const float*)d_in[14];
  const float* db2 = (const float*)d_in[15];
  const float* d_lnw = (const float*)d_in[16];
  const float* d_lnb = (const float*)d_in[17];

  char* ws = (char*)d_ws;
  f16* wts  = (f16*)(ws + 0);            // 4 x 16384 f16 fragment-ordered = 128 KB
  f16* qW1f = wts;
  f16* qW2f = wts + 16384;
  f16* dW1f = wts + 32768;
  f16* dW2f = wts + 49152;
  f16* qv   = (f16*)(ws + 131072);       // [64][1024][8] f16 fragment-A order = 1 MB
  float* partials = (float*)(ws + 131072 + 1048576);  // [64][64][64] f32 = 1 MB
  float* out = (float*)d_out;

  prep_kernel<<<32, 256, 0, stream>>>(qW1, qW2, dW1, dW2, wts);
  qencode_kernel<<<64, 256, 0, stream>>>(query_ids, query_mask, q_emb,
                                         qW1f, qb1, qW2f, qb2, q_lnw, q_lnb, qv);
  docsim_kernel<<<2048, 512, 0, stream>>>(doc_ids, doc_mask, d_emb,
                                          dW1f, db1, dW2f, db2, d_lnw, d_lnb,
                                          qv, partials);
  reduce_kernel<<<64, 256, 0, stream>>>(partials, out);
}

// Round 4
// 182.629 us; speedup vs baseline: 1.2169x; 1.2169x over previous
//
#include <hip/hip_runtime.h>

typedef _Float16 f16;
typedef __attribute__((ext_vector_type(8))) _Float16 f16x8;
typedef __attribute__((ext_vector_type(4))) float f32x4;

#define XS 136            // padded LDS row stride in f16 elems (128 + 8)
#define NEGV (-1e30f)

// ---------- helpers ----------

__device__ __forceinline__ void stage_emb(const int* __restrict__ ids,
                                          const float* __restrict__ emb,
                                          f16* Xs, int tid) {
  // tokens x 128 f32 -> f16 LDS. thread: token tid/4 (wave-private rows:
  // wave w stages exactly rows [16w, 16w+16) — no barrier needed before
  // this wave reads its own A-fragments).
  int t = tid >> 2, seg = tid & 3;
  int id = ids[t];
  const float4* src = (const float4*)(emb + (size_t)id * 128 + seg * 32);
  f16x8* dst = (f16x8*)(Xs + t * XS + seg * 32);
#pragma unroll
  for (int i = 0; i < 4; ++i) {
    float4 v0 = src[2 * i], v1 = src[2 * i + 1];
    f16x8 o;
    o[0] = (f16)v0.x; o[1] = (f16)v0.y; o[2] = (f16)v0.z; o[3] = (f16)v0.w;
    o[4] = (f16)v1.x; o[5] = (f16)v1.y; o[6] = (f16)v1.z; o[7] = (f16)v1.w;
    dst[i] = o;
  }
}

__device__ __forceinline__ void load_afrag(f16x8* afrag, const f16* Xs,
                                           int wave, int lane) {
  const int r = lane & 15, quad = lane >> 4;
#pragma unroll
  for (int k = 0; k < 4; ++k)
    afrag[k] = *(const f16x8*)(Xs + (wave * 16 + r) * XS + quad * 8 + k * 32);
}

// full 128-out layer GEMM with B-fragments streamed DIRECTLY from global
// (fragment-ordered W; every wave reads the same 32KB stream -> L1/L2 hits).
__device__ __forceinline__ void layer_mfma(f32x4* acc, const f16x8* afrag,
                                           const f16* __restrict__ Wf, int lane) {
  const f16* Wl = Wf + lane * 8;
#pragma unroll
  for (int nt = 0; nt < 8; ++nt) {
    f32x4 c = {0.f, 0.f, 0.f, 0.f};
#pragma unroll
    for (int k = 0; k < 4; ++k) {
      f16x8 b = *(const f16x8*)(Wl + (nt * 4 + k) * 512);
      c = __builtin_amdgcn_mfma_f32_16x16x32_f16(afrag[k], b, c, 0, 0, 0);
    }
    acc[nt] = c;
  }
}

// bias + relu + layernorm, write h back to Xs (wave-private rows)
__device__ __forceinline__ void epilogue_ln(f32x4* acc, int wave, int lane, f16* Xs,
                                            const float* __restrict__ bias,
                                            const float* __restrict__ lnw,
                                            const float* __restrict__ lnb) {
  const int r = lane & 15, quad = lane >> 4;
  float s1[4] = {0, 0, 0, 0}, s2[4] = {0, 0, 0, 0};
#pragma unroll
  for (int nt = 0; nt < 8; ++nt) {
    float bv = bias[nt * 16 + r];
#pragma unroll
    for (int g = 0; g < 4; ++g) {
      float z = fmaxf(acc[nt][g] + bv, 0.f);
      acc[nt][g] = z; s1[g] += z; s2[g] += z * z;
    }
  }
#pragma unroll
  for (int off = 1; off < 16; off <<= 1) {
#pragma unroll
    for (int g = 0; g < 4; ++g) {
      s1[g] += __shfl_xor(s1[g], off);
      s2[g] += __shfl_xor(s2[g], off);
    }
  }
  float mean[4], rstd[4];
#pragma unroll
  for (int g = 0; g < 4; ++g) {
    mean[g] = s1[g] * (1.f / 128.f);
    rstd[g] = rsqrtf(s2[g] * (1.f / 128.f) - mean[g] * mean[g] + 1e-5f);
  }
#pragma unroll
  for (int nt = 0; nt < 8; ++nt) {
    float w = lnw[nt * 16 + r], bb = lnb[nt * 16 + r];
#pragma unroll
    for (int g = 0; g < 4; ++g) {
      float h = (acc[nt][g] - mean[g]) * rstd[g] * w + bb;
      Xs[(wave * 16 + quad * 4 + g) * XS + nt * 16 + r] = (f16)h;
    }
  }
}

// ---------- kernels ----------

// W[k][n] f32 -> fragment-ordered f16: out[((nt*4+k)*64 + quad*16 + r)*8 + j]
//   = W[k*32 + quad*8 + j][nt*16 + r]
__global__ __launch_bounds__(256) void prep_kernel(
    const float* __restrict__ qW1, const float* __restrict__ qW2,
    const float* __restrict__ dW1, const float* __restrict__ dW2,
    f16* __restrict__ out) {
  int mat = blockIdx.x >> 3;   // 8 blocks per matrix
  int blk = blockIdx.x & 7;
  const float* W = mat == 0 ? qW1 : mat == 1 ? qW2 : mat == 2 ? dW1 : dW2;
  int u = blk * 256 + threadIdx.x;                 // fragment-lane unit 0..2047
  int r = u & 15, quad = (u >> 4) & 3, k = (u >> 6) & 3, nt = u >> 8;
  const float* src = W + (k * 32 + quad * 8) * 128 + nt * 16 + r;
  f16x8 o;
#pragma unroll
  for (int j = 0; j < 8; ++j) o[j] = (f16)src[j * 128];
  *(f16x8*)(out + (size_t)mat * 16384 + (size_t)u * 8) = o;
}

__global__ __launch_bounds__(256) void qencode_kernel(
    const int* __restrict__ qids, const int* __restrict__ qmask,
    const float* __restrict__ emb,
    const f16* __restrict__ W1f, const float* __restrict__ b1,
    const f16* __restrict__ W2f, const float* __restrict__ b2,
    const float* __restrict__ lnw, const float* __restrict__ lnb,
    f16* __restrict__ qv) {
  __shared__ __align__(16) f16 Xs[64 * XS];
  const int tid = threadIdx.x, wave = tid >> 6, lane = tid & 63;
  const int b = blockIdx.x;
  stage_emb(qids + b * 64, emb, Xs, tid);
  f32x4 acc[8];
  f16x8 afrag[4];
  load_afrag(afrag, Xs, wave, lane);          // own rows — no barrier
  layer_mfma(acc, afrag, W1f, lane);
  epilogue_ln(acc, wave, lane, Xs, b1, lnw, lnb);
  load_afrag(afrag, Xs, wave, lane);
  layer_mfma(acc, afrag, W2f, lane);
  epilogue_ln(acc, wave, lane, Xs, b2, lnw, lnb);
  __syncthreads();                            // copy-out reads all rows
  // masked copy-out in A-fragment order: qv[b][u][8]
#pragma unroll
  for (int i = 0; i < 4; ++i) {
    int u = tid + i * 256;               // 1024 units of f16x8
    int r = u & 15, quad = (u >> 4) & 3, k = (u >> 6) & 3, mt = u >> 8;
    int row = mt * 16 + r;
    f16 m = (f16)(float)qmask[b * 64 + row];
    f16x8 v = *(const f16x8*)(Xs + row * XS + k * 32 + quad * 8);
#pragma unroll
    for (int j = 0; j < 8; ++j) v[j] = v[j] * m;
    *(f16x8*)(qv + (size_t)b * 8192 + (size_t)u * 8) = v;
  }
}

// 256 threads / 4 waves / one 64-doc chunk. Encoder is barrier-free
// (Xs rows are wave-private; W streams from global). ONE barrier total.
__global__ __launch_bounds__(256) void docsim_kernel(
    const int* __restrict__ dids, const int* __restrict__ dmask,
    const float* __restrict__ emb,
    const f16* __restrict__ W1f, const float* __restrict__ b1,
    const f16* __restrict__ W2f, const float* __restrict__ b2,
    const float* __restrict__ lnw, const float* __restrict__ lnb,
    const f16* __restrict__ qv, float* __restrict__ partials) {
  __shared__ __align__(16) f16 Xs[64 * XS];   // 17,408 B — the only LDS
  const int tid = threadIdx.x, wave = tid >> 6, lane = tid & 63;
  const int b = blockIdx.x >> 6;    // batch
  const int dc = blockIdx.x & 63;   // doc chunk of 64
  const int r = lane & 15, quad = lane >> 4;
  // doc-mask for this lane's sim columns — independent early loads
  float mv[4];
#pragma unroll
  for (int nt = 0; nt < 4; ++nt)
    mv[nt] = (float)dmask[(size_t)b * 4096 + dc * 64 + nt * 16 + r];
  // sim A-fragments (fragment-ordered qv) — early, fully independent
  f16x8 qfrag[4];
#pragma unroll
  for (int k = 0; k < 4; ++k) {
    int u = (wave * 4 + k) * 64 + quad * 16 + r;
    qfrag[k] = *(const f16x8*)(qv + (size_t)b * 8192 + (size_t)u * 8);
  }
  stage_emb(dids + (size_t)b * 4096 + dc * 64, emb, Xs, tid);
  f32x4 acc[8];
  f16x8 afrag[4];
  load_afrag(afrag, Xs, wave, lane);          // own rows — no barrier
  layer_mfma(acc, afrag, W1f, lane);
  epilogue_ln(acc, wave, lane, Xs, b1, lnw, lnb);
  load_afrag(afrag, Xs, wave, lane);
  layer_mfma(acc, afrag, W2f, lane);
  epilogue_ln(acc, wave, lane, Xs, b2, lnw, lnb);
  __syncthreads();                            // the ONLY barrier: dv all-visible
  float rowmax[4] = {NEGV, NEGV, NEGV, NEGV};
#pragma unroll
  for (int nt = 0; nt < 4; ++nt) {
    f32x4 c = {0.f, 0.f, 0.f, 0.f};
#pragma unroll
    for (int k = 0; k < 4; ++k) {
      f16x8 bfrag = *(const f16x8*)(Xs + (nt * 16 + r) * XS + quad * 8 + k * 32);
      c = __builtin_amdgcn_mfma_f32_16x16x32_f16(qfrag[k], bfrag, c, 0, 0, 0);
    }
#pragma unroll
    for (int g = 0; g < 4; ++g) {
      float v = (mv[nt] != 0.f) ? c[g] : NEGV;
      rowmax[g] = fmaxf(rowmax[g], v);
    }
  }
#pragma unroll
  for (int off = 1; off < 16; off <<= 1) {
#pragma unroll
    for (int g = 0; g < 4; ++g)
      rowmax[g] = fmaxf(rowmax[g], __shfl_xor(rowmax[g], off));
  }
  if (r == 0) {
#pragma unroll
    for (int g = 0; g < 4; ++g) {
      int q = wave * 16 + quad * 4 + g;
      partials[((size_t)b * 64 + q) * 64 + dc] = rowmax[g];
    }
  }
}

__global__ __launch_bounds__(256) void reduce_kernel(
    const float* __restrict__ partials, float* __restrict__ out) {
  __shared__ float red[64][4];
  const int b = blockIdx.x, tid = threadIdx.x;
  const int q = tid >> 2, seg = tid & 3;
  const float4* p = (const float4*)(partials + ((size_t)b * 64 + q) * 64 + seg * 16);
  float m = NEGV;
#pragma unroll
  for (int i = 0; i < 4; ++i) {
    float4 v = p[i];
    m = fmaxf(m, fmaxf(fmaxf(v.x, v.y), fmaxf(v.z, v.w)));
  }
  red[q][seg] = m;
  __syncthreads();
  if (tid < 64) {
    float qm = fmaxf(fmaxf(red[tid][0], red[tid][1]), fmaxf(red[tid][2], red[tid][3]));
    float s = qm;
#pragma unroll
    for (int off = 1; off < 64; off <<= 1) s += __shfl_xor(s, off);
    if (tid == 0) out[b] = s;
  }
}

// ---------- launch ----------

extern "C" void kernel_launch(void* const* d_in, const int* in_sizes, int n_in,
                              void* d_out, int out_size, void* d_ws, size_t ws_size,
                              hipStream_t stream) {
  const int* query_ids  = (const int*)d_in[0];
  const int* doc_ids    = (const int*)d_in[1];
  const int* query_mask = (const int*)d_in[2];
  const int* doc_mask   = (const int*)d_in[3];
  const float* q_emb = (const float*)d_in[4];
  const float* qW1 = (const float*)d_in[5];
  const float* qb1 = (const float*)d_in[6];
  const float* qW2 = (const float*)d_in[7];
  const float* qb2 = (const float*)d_in[8];
  const float* q_lnw = (const float*)d_in[9];
  const float* q_lnb = (const float*)d_in[10];
  const float* d_emb = (const float*)d_in[11];
  const float* dW1 = (const float*)d_in[12];
  const float* db1 = (const float*)d_in[13];
  const float* dW2 = (const float*)d_in[14];
  const float* db2 = (const float*)d_in[15];
  const float* d_lnw = (const float*)d_in[16];
  const float* d_lnb = (const float*)d_in[17];

  char* ws = (char*)d_ws;
  f16* wts  = (f16*)(ws + 0);            // 4 x 16384 f16 fragment-ordered = 128 KB
  f16* qW1f = wts;
  f16* qW2f = wts + 16384;
  f16* dW1f = wts + 32768;
  f16* dW2f = wts + 49152;
  f16* qv   = (f16*)(ws + 131072);       // [64][1024][8] f16 fragment-A order = 1 MB
  float* partials = (float*)(ws + 131072 + 1048576);  // [64][64][64] f32 = 1 MB
  float* out = (float*)d_out;

  prep_kernel<<<32, 256, 0, stream>>>(qW1, qW2, dW1, dW2, wts);
  qencode_kernel<<<64, 256, 0, stream>>>(query_ids, query_mask, q_emb,
                                         qW1f, qb1, qW2f, qb2, q_lnw, q_lnb, qv);
  docsim_kernel<<<4096, 256, 0, stream>>>(doc_ids, doc_mask, d_emb,
                                          dW1f, db1, dW2f, db2, d_lnw, d_lnb,
                                          qv, partials);
  reduce_kernel<<<64, 256, 0, stream>>>(partials, out);
}